// Round 17
// baseline (31.723 us; speedup 1.0000x reference)
//
#include <hip/hip_runtime.h>

#define B_N 8192
#define K_CL 64
#define CAP 256
#define NPAIR 2016
#define INF_F 3.0e38f

// R17: the untried cell of the structure matrix — FUSED pair kernel with
// UNCONDITIONAL register preload (R13's fix applied to R15's fused form).
// Theory: R15's 36us came from 32 rounds of exec-masked scattered coord
// loads serializing at L2 latency; preloading labels+coords into registers
// (96KB/block coalesced, 190MB aggregate ~5.3us at L2 BW) leaves only
// register-conditional LDS *stores* (fire-and-forget) in the divergent loop.
// 2 dispatches; reduce launch setup hides behind the ~10us fused kernel.
// ws: hinges float[2016]

__global__ __launch_bounds__(256) void fused_pair_kernel(
    const int* __restrict__ labels, const float* __restrict__ coords,
    float* __restrict__ hinges) {
    int p = blockIdx.x;                    // 0..2015
    int ci = 0, rem = p;                   // decode p -> (ci<cj), uniform
    while (rem >= K_CL - 1 - ci) { rem -= K_CL - 1 - ci; ci++; }
    int cj = ci + 1 + rem;
    int tid = threadIdx.x, lane = tid & 63, wave = tid >> 6;

    __shared__ float2 ipt[CAP], jpt[CAP];
    __shared__ int wsum[4];
    __shared__ float wred[4];

    // unconditional preload: 32 labels + 32 points per thread (coalesced,
    // L2-hot across 2016 blocks; full memory-level parallelism)
    int4 lb[8];
    float4 cr[16];
    const int4*   l4 = reinterpret_cast<const int4*>(labels);
    const float4* c4 = reinterpret_cast<const float4*>(coords);
#pragma unroll
    for (int k = 0; k < 8; ++k) {
        int v4 = tid + k * 256;
        lb[k]       = l4[v4];
        cr[2*k]     = c4[2*v4];
        cr[2*k + 1] = c4[2*v4 + 1];
    }

    int cntI = 0, cntJ = 0;
#pragma unroll
    for (int k = 0; k < 8; ++k) {
        cntI += (lb[k].x==ci) + (lb[k].y==ci) + (lb[k].z==ci) + (lb[k].w==ci);
        cntJ += (lb[k].x==cj) + (lb[k].y==cj) + (lb[k].z==cj) + (lb[k].w==cj);
    }

    // ONE packed exclusive scan for both counters (I<<16 | J)
    int pack = (cntI << 16) | cntJ;
    int incl = pack;
#pragma unroll
    for (int d = 1; d < 64; d <<= 1) {
        int u = __shfl_up(incl, d, 64);
        if (lane >= d) incl += u;
    }
    if (lane == 63) wsum[wave] = incl;
    __syncthreads();
    int wbase = 0, tot = 0;
#pragma unroll
    for (int w = 0; w < 4; ++w) {
        wbase += (w < wave) ? wsum[w] : 0;
        tot += wsum[w];
    }
    int basep = wbase + incl - pack;
    int posI = basep >> 16, posJ = basep & 0xffff;
    int nI = min(tot >> 16, CAP), nJ = min(tot & 0xffff, CAP);

    // divergent loop touches REGISTERS + LDS stores only (no loads)
#pragma unroll
    for (int k = 0; k < 8; ++k) {
        float2 p0 = make_float2(cr[2*k].x,     cr[2*k].y);
        float2 p1 = make_float2(cr[2*k].z,     cr[2*k].w);
        float2 p2 = make_float2(cr[2*k + 1].x, cr[2*k + 1].y);
        float2 p3 = make_float2(cr[2*k + 1].z, cr[2*k + 1].w);
        int lab[4] = {lb[k].x, lb[k].y, lb[k].z, lb[k].w};
        float2 pt[4] = {p0, p1, p2, p3};
#pragma unroll
        for (int cc = 0; cc < 4; ++cc) {
            if (lab[cc] == ci) {
                if (posI < CAP) ipt[posI] = pt[cc];
                posI++;
            } else if (lab[cc] == cj) {
                if (posJ < CAP) jpt[posJ] = pt[cc];
                posJ++;
            }
        }
    }
    __syncthreads();

    // 2 threads per i-point, 4-accumulator unrolled j-half (proven R13)
    int half = (nJ + 1) >> 1;
    int j0 = (tid & 1) ? half : 0;
    int j1 = (tid & 1) ? nJ : half;
    float m0 = INF_F, m1 = INF_F, m2 = INF_F, m3 = INF_F;
    for (int i = tid >> 1; i < nI; i += 128) {
        float2 pi = ipt[i];
        int j = j0;
        for (; j + 3 < j1; j += 4) {
            float2 a = jpt[j], b = jpt[j+1], c = jpt[j+2], d = jpt[j+3];
            float dx0 = pi.x - a.x, dy0 = pi.y - a.y;
            float dx1 = pi.x - b.x, dy1 = pi.y - b.y;
            float dx2 = pi.x - c.x, dy2 = pi.y - c.y;
            float dx3 = pi.x - d.x, dy3 = pi.y - d.y;
            m0 = fminf(m0, dx0*dx0 + dy0*dy0);
            m1 = fminf(m1, dx1*dx1 + dy1*dy1);
            m2 = fminf(m2, dx2*dx2 + dy2*dy2);
            m3 = fminf(m3, dx3*dx3 + dy3*dy3);
        }
        for (; j < j1; ++j) {
            float dx = pi.x - jpt[j].x, dy = pi.y - jpt[j].y;
            m0 = fminf(m0, dx*dx + dy*dy);
        }
    }
    float myMin = fminf(fminf(m0, m1), fminf(m2, m3));

    for (int off = 32; off > 0; off >>= 1)
        myMin = fminf(myMin, __shfl_down(myMin, off, 64));
    if (lane == 0) wred[wave] = myMin;
    __syncthreads();
    if (tid == 0) {
        float m = fminf(fminf(wred[0], wred[1]), fminf(wred[2], wred[3]));
        float h = 1.0f - sqrtf(m);
        hinges[p] = h > 0.0f ? h : 0.0f;
    }
}

__global__ void reduce_hinge_kernel(const float* __restrict__ hinges,
                                    float* __restrict__ out) {
    int tid = threadIdx.x;
    float s = 0.0f;
    for (int p = tid; p < NPAIR; p += 256) s += hinges[p];
    for (int off = 32; off > 0; off >>= 1)
        s += __shfl_down(s, off, 64);
    __shared__ float wsum[4];
    int wave = tid >> 6, lane = tid & 63;
    if (lane == 0) wsum[wave] = s;
    __syncthreads();
    if (tid == 0)
        out[0] = (wsum[0] + wsum[1] + wsum[2] + wsum[3]) / (float)NPAIR;
}

extern "C" void kernel_launch(void* const* d_in, const int* in_sizes, int n_in,
                              void* d_out, int out_size, void* d_ws, size_t ws_size,
                              hipStream_t stream) {
    const int*   labels = (const int*)d_in[1];     // cluster_labels (int32)
    const float* coords = (const float*)d_in[2];   // manifold_coords [8192,2] f32
    float* out    = (float*)d_out;
    float* hinges = (float*)d_ws;

    fused_pair_kernel<<<NPAIR, 256, 0, stream>>>(labels, coords, hinges);
    reduce_hinge_kernel<<<1, 256, 0, stream>>>(hinges, out);
}